// Round 9
// baseline (9022.163 us; speedup 1.0000x reference)
//
#include <hip/hip_runtime.h>

// LSTM decoder B=64,S=512,D=512,H=512,L=2 — Round 9: XCD-local recurrences.
// Block decode (assumes round-robin XCD = blockIdx%8, perf-only assumption):
//   xcd = b&7; group g = xcd>>1 (16 batches); role = xcd&1 (layer); us = b>>3.
// Each XCD: 32 blocks = one layer x one batch-group; 4MB weight slice fits L2.
// h exchange: tagged words (epoch<<16|bf16), 8-deep buffers.
//   producer: plain store (local L2) + sc1 store (L3, correctness fallback)
//   consumer: batched sc0 loads (L2) -> tag validate -> sc1 retry fallback.
// Cross-layer h0->L1 read is sc1-direct, issued concurrently with local batch.
// No per-step flags; 4-step anti-dep progress gate only.

#define NB 64
#define NS 512
#define ND 512
#define NH 512

typedef __attribute__((ext_vector_type(8))) short short8;
typedef __attribute__((ext_vector_type(4))) float f32x4;
typedef __attribute__((ext_vector_type(4))) unsigned int u32x4;

// ---- ws layout (bytes) ----
#define WPK_OFF   0                  // 8,388,608
#define HT0_OFF   8388608            // 4 grp * 8 bufs * 16*512 u32 = 1MB
#define HT1_OFF   9437184            // 1MB
#define FLAGS_OFF 10485760           // 256 u32
#define WPK_ELEMS_PER_ROLE (128 * 32 * 512)
#define GRP_STRIDE 65536             // u32 per group
#define BUF_STRIDE 8192              // u32 per buffer (16*512)

__device__ __forceinline__ unsigned int pack2bf(float a, float b) {
    unsigned int ua = __builtin_bit_cast(unsigned int, a);
    unsigned int ub = __builtin_bit_cast(unsigned int, b);
    ua += 0x7fffu + ((ua >> 16) & 1u);   // RNE
    ub += 0x7fffu + ((ub >> 16) & 1u);
    return (ua >> 16) | (ub & 0xffff0000u);
}
__device__ __forceinline__ unsigned short bf16r(float a) {
    unsigned int ua = __builtin_bit_cast(unsigned int, a);
    ua += 0x7fffu + ((ua >> 16) & 1u);
    return (unsigned short)(ua >> 16);
}

__device__ __forceinline__ unsigned int ld_flag(const unsigned int* p) {
    return __hip_atomic_load(p, __ATOMIC_RELAXED, __HIP_MEMORY_SCOPE_AGENT);
}
__device__ __forceinline__ void st_flag(unsigned int* p, unsigned int v) {
    __hip_atomic_store(p, v, __ATOMIC_RELAXED, __HIP_MEMORY_SCOPE_AGENT);
}

__device__ __forceinline__ bool tag8_ok(const u32x4& a, const u32x4& b, unsigned int T16) {
    unsigned int m = ((a.x >> 16) ^ T16) | ((a.y >> 16) ^ T16)
                   | ((a.z >> 16) ^ T16) | ((a.w >> 16) ^ T16)
                   | ((b.x >> 16) ^ T16) | ((b.y >> 16) ^ T16)
                   | ((b.z >> 16) ^ T16) | ((b.w >> 16) ^ T16);
    return m == 0;
}
__device__ __forceinline__ u32x4 pack8(const u32x4& a, const u32x4& b) {
    u32x4 r;
    r.x = (a.x & 0xFFFFu) | (a.y << 16);
    r.y = (a.z & 0xFFFFu) | (a.w << 16);
    r.z = (b.x & 0xFFFFu) | (b.y << 16);
    r.w = (b.z & 0xFFFFu) | (b.w << 16);
    return r;
}

// issue 8 dwordx4 loads (4 slots x 32B), no wait. LOCAL: sc0 (L2). else sc0 sc1 (L3).
template<bool LOCAL>
__device__ __forceinline__ void batch4_nw(const unsigned int* p0, const unsigned int* p1,
                                          const unsigned int* p2, const unsigned int* p3,
                                          u32x4& a0, u32x4& b0, u32x4& a1, u32x4& b1,
                                          u32x4& a2, u32x4& b2, u32x4& a3, u32x4& b3) {
    if constexpr (LOCAL) {
        asm volatile(
            "global_load_dwordx4 %0, %8, off sc0\n\t"
            "global_load_dwordx4 %1, %8, off offset:16 sc0\n\t"
            "global_load_dwordx4 %2, %9, off sc0\n\t"
            "global_load_dwordx4 %3, %9, off offset:16 sc0\n\t"
            "global_load_dwordx4 %4, %10, off sc0\n\t"
            "global_load_dwordx4 %5, %10, off offset:16 sc0\n\t"
            "global_load_dwordx4 %6, %11, off sc0\n\t"
            "global_load_dwordx4 %7, %11, off offset:16 sc0"
            : "=&v"(a0), "=&v"(b0), "=&v"(a1), "=&v"(b1),
              "=&v"(a2), "=&v"(b2), "=&v"(a3), "=&v"(b3)
            : "v"(p0), "v"(p1), "v"(p2), "v"(p3)
            : "memory");
    } else {
        asm volatile(
            "global_load_dwordx4 %0, %8, off sc0 sc1\n\t"
            "global_load_dwordx4 %1, %8, off offset:16 sc0 sc1\n\t"
            "global_load_dwordx4 %2, %9, off sc0 sc1\n\t"
            "global_load_dwordx4 %3, %9, off offset:16 sc0 sc1\n\t"
            "global_load_dwordx4 %4, %10, off sc0 sc1\n\t"
            "global_load_dwordx4 %5, %10, off offset:16 sc0 sc1\n\t"
            "global_load_dwordx4 %6, %11, off sc0 sc1\n\t"
            "global_load_dwordx4 %7, %11, off offset:16 sc0 sc1"
            : "=&v"(a0), "=&v"(b0), "=&v"(a1), "=&v"(b1),
              "=&v"(a2), "=&v"(b2), "=&v"(a3), "=&v"(b3)
            : "v"(p0), "v"(p1), "v"(p2), "v"(p3)
            : "memory");
    }
}
__device__ __forceinline__ void vm_wait0() {
    asm volatile("s_waitcnt vmcnt(0)" ::: "memory");
    __builtin_amdgcn_sched_barrier(0);
}

// single-slot blocking retry; LOCAL tries sc0 32x then escalates to sc1.
template<bool LOCAL>
__device__ __forceinline__ void slot_retry(const unsigned int* p, unsigned int T16,
                                           u32x4& a, u32x4& b) {
    int tries = 0;
    for (;;) {
        if (LOCAL && tries < 32) {
            asm volatile(
                "global_load_dwordx4 %0, %2, off sc0\n\t"
                "global_load_dwordx4 %1, %2, off offset:16 sc0\n\t"
                "s_waitcnt vmcnt(0)"
                : "=&v"(a), "=&v"(b) : "v"(p) : "memory");
        } else {
            asm volatile(
                "global_load_dwordx4 %0, %2, off sc0 sc1\n\t"
                "global_load_dwordx4 %1, %2, off offset:16 sc0 sc1\n\t"
                "s_waitcnt vmcnt(0)"
                : "=&v"(a), "=&v"(b) : "v"(p) : "memory");
        }
        __builtin_amdgcn_sched_barrier(0);
        if (tag8_ok(a, b, T16)) return;
        ++tries;
        if (tries > 64) __builtin_amdgcn_s_sleep(1);
    }
}

// Repack weights into MFMA B-fragment order (unchanged from R7):
__global__ void prep_weights_k(const float* __restrict__ W_ih,
                               const float* __restrict__ W_hh,
                               unsigned int* __restrict__ wpk_u32) {
    long long gid = (long long)blockIdx.x * blockDim.x + threadIdx.x; // 524288
    int l   = (int)(gid & 63);
    int k0i = (int)((gid >> 6) & 31);
    int nt  = (int)((gid >> 11) & 127);
    int r   = (int)(gid >> 18);
    int n = nt * 16 + (l & 15);
    int k = k0i * 32 + ((l >> 4) << 3);
    const float* src;
    if (k < 512) src = W_ih + ((long long)r * 2048 + n) * 512 + k;
    else         src = W_hh + ((long long)r * 2048 + n) * 512 + (k - 512);
    uint4 v;
    v.x = pack2bf(src[0], src[1]);
    v.y = pack2bf(src[2], src[3]);
    v.z = pack2bf(src[4], src[5]);
    v.w = pack2bf(src[6], src[7]);
    ((uint4*)wpk_u32)[gid] = v;
}

// Clear all tag buffers (every call — kills stale tags from prior replays);
// h_{-1} = enc_h with tag 0 into buf 7 of both arrays.
__global__ void prep_state_k(const float* __restrict__ eh,
                             unsigned int* __restrict__ ht0,
                             unsigned int* __restrict__ ht1,
                             unsigned int* __restrict__ flags) {
    int gid = blockIdx.x * blockDim.x + threadIdx.x;  // 262144
    if (gid < 4 * GRP_STRIDE) {
        int g   = gid >> 16;
        int rem = gid & 65535;
        int buf = rem >> 13;
        int idx = rem & 8191;
        unsigned int v = 0;
        if (buf == 7) {
            int row = idx >> 9, u = idx & 511;
            v = (unsigned int)bf16r(eh[(g * 16 + row) * 512 + u]);
        }
        ht0[gid] = v;
        ht1[gid] = v;
    }
    if (gid < 256) flags[gid] = 0;
}

__global__ __launch_bounds__(256, 1)
void lstm_persist_k(const float* __restrict__ input,
                    const float* __restrict__ enc_c,
                    const float* __restrict__ b_ih,
                    const float* __restrict__ b_hh,
                    const unsigned short* __restrict__ wpk,
                    unsigned int* __restrict__ ht0,
                    unsigned int* __restrict__ ht1,
                    float* __restrict__ out,
                    unsigned int* __restrict__ flags) {
    __shared__ alignas(16) unsigned char smem[32768];
    const int bid  = blockIdx.x;
    const int xcd  = bid & 7;
    const int grp  = xcd >> 1;            // batch group 0..3 (16 batches)
    const int role = xcd & 1;             // 0: layer0(i), 1: layer1(i-1)
    const int us   = bid >> 3;            // unit block 0..31
    const int m0   = grp << 4;
    const int tid  = threadIdx.x;
    const int lane = tid & 63;
    const int tq   = tid >> 6;
    const int gq   = __builtin_amdgcn_readfirstlane(tq);   // wave = gate

    const unsigned short* wp = wpk + (long long)role * WPK_ELEMS_PER_ROLE
                             + (long long)(gq * 32 + us) * (32 * 512);
    unsigned int* ht0g = ht0 + grp * GRP_STRIDE;
    unsigned int* ht1g = ht1 + grp * GRP_STRIDE;
    unsigned int* myflag   = flags + (grp << 6) + (role << 5) + us;
    const unsigned int* gf = flags + (grp << 6) + lane;

    // staging geometry (per thread, 4 slots per half)
    const int srow  = tid & 15;
    const int skoff = ((tid & 63) >> 4) << 3;

    // ---- per-thread cell state + biases ----
    const int m_l = tid >> 4, u_l = tid & 15;
    const int bcell = m0 + m_l;
    const int ucell = us * 16 + u_l;
    float cReg = enc_c[bcell * NH + ucell];
    const long long br = (long long)role * 2048;
    const float bias_i = b_ih[br + 0 * 512 + ucell] + b_hh[br + 0 * 512 + ucell];
    const float bias_f = b_ih[br + 1 * 512 + ucell] + b_hh[br + 1 * 512 + ucell];
    const float bias_g = b_ih[br + 2 * 512 + ucell] + b_hh[br + 2 * 512 + ucell];
    const float bias_o = b_ih[br + 3 * 512 + ucell] + b_hh[br + 3 * 512 + ucell];

    // ---- role0: prefetch x(0) ----
    float4 xp[8];
    if (role == 0) {
        #pragma unroll
        for (int ii = 0; ii < 4; ++ii) {
            int k0i = ii * 4 + tq;
            const float* s = input + (long long)(m0 + (tid & 15)) * (NS * ND)
                                   + k0i * 32 + skoff;
            xp[2 * ii]     = *(const float4*)s;
            xp[2 * ii + 1] = *(const float4*)(s + 4);
        }
    }

    for (int i = 0; i <= NS; ++i) {
        const bool active = (role == 0) ? (i < NS) : (i >= 1);

        // ---- anti-dep gate: every 4 steps, all group peers' progress >= i-3 ----
        if ((i & 3) == 0 && i >= 4) {
            if (tid < 64) {
                unsigned int need = (unsigned int)(i - 3);
                for (;;) {
                    unsigned int v = ld_flag(gf);
                    if (__ballot(v >= need) == 0xFFFFFFFFFFFFFFFFULL) break;
                    __builtin_amdgcn_s_sleep(1);
                }
            }
        }

        if (active) {
            const unsigned int* slotbase;   // thread's slot 0 ptr pattern
            if (role == 0) {
                // issue local h0_{i-1} batch (slots -> LDS half 2), overlap with x-pack
                const unsigned int* hb = ht0g + ((i - 1) & 7) * BUF_STRIDE;
                const unsigned int T16 = (unsigned int)i;
                slotbase = hb + srow * 512 + tq * 32 + skoff;
                u32x4 a0,b0,a1,b1,a2,b2,a3,b3;
                batch4_nw<true>(slotbase, slotbase + 128, slotbase + 256, slotbase + 384,
                                a0,b0,a1,b1,a2,b2,a3,b3);
                // x-part from prefetched regs (LDS, doesn't touch vmcnt)
                #pragma unroll
                for (int ii = 0; ii < 4; ++ii) {
                    int sid = ii * 256 + tid;
                    float4 lo = xp[2 * ii], hi = xp[2 * ii + 1];
                    u32x4 val;
                    val.x = pack2bf(lo.x, lo.y);
                    val.y = pack2bf(lo.z, lo.w);
                    val.z = pack2bf(hi.x, hi.y);
                    val.w = pack2bf(hi.z, hi.w);
                    *(u32x4*)(smem + sid * 16) = val;
                }
                vm_wait0();
                if (!tag8_ok(a0, b0, T16)) slot_retry<true>(slotbase,       T16, a0, b0);
                if (!tag8_ok(a1, b1, T16)) slot_retry<true>(slotbase + 128, T16, a1, b1);
                if (!tag8_ok(a2, b2, T16)) slot_retry<true>(slotbase + 256, T16, a2, b2);
                if (!tag8_ok(a3, b3, T16)) slot_retry<true>(slotbase + 384, T16, a3, b3);
                *(u32x4*)(smem + (1024 + 0 * 256 + tid) * 16) = pack8(a0, b0);
                *(u32x4*)(smem + (1024 + 1 * 256 + tid) * 16) = pack8(a1, b1);
                *(u32x4*)(smem + (1024 + 2 * 256 + tid) * 16) = pack8(a2, b2);
                *(u32x4*)(smem + (1024 + 3 * 256 + tid) * 16) = pack8(a3, b3);
            } else {
                // x = h0_{i-1} (cross-XCD, sc1) ; h = h1_{i-2} (local, sc0)
                const unsigned int* xb = ht0g + ((i - 1) & 7) * BUF_STRIDE;
                const unsigned int* hb = ht1g + ((i - 2) & 7) * BUF_STRIDE;
                const unsigned int Tx = (unsigned int)i;
                const unsigned int Th = (unsigned int)(i - 1);
                const unsigned int* px = xb + srow * 512 + tq * 32 + skoff;
                const unsigned int* ph = hb + srow * 512 + tq * 32 + skoff;
                u32x4 xa0,xb0,xa1,xb1,xa2,xb2,xa3,xb3;
                u32x4 ha0,hb0,ha1,hb1,ha2,hb2,ha3,hb3;
                batch4_nw<false>(px, px + 128, px + 256, px + 384,
                                 xa0,xb0,xa1,xb1,xa2,xb2,xa3,xb3);
                batch4_nw<true>(ph, ph + 128, ph + 256, ph + 384,
                                ha0,hb0,ha1,hb1,ha2,hb2,ha3,hb3);
                vm_wait0();
                if (!tag8_ok(xa0, xb0, Tx)) slot_retry<false>(px,       Tx, xa0, xb0);
                if (!tag8_ok(xa1, xb1, Tx)) slot_retry<false>(px + 128, Tx, xa1, xb1);
                if (!tag8_ok(xa2, xb2, Tx)) slot_retry<false>(px + 256, Tx, xa2, xb2);
                if (!tag8_ok(xa3, xb3, Tx)) slot_retry<false>(px + 384, Tx, xa3, xb3);
                if (!tag8_ok(ha0, hb0, Th)) slot_retry<true>(ph,        Th, ha0, hb0);
                if (!tag8_ok(ha1, hb1, Th)) slot_retry<true>(ph + 128,  Th, ha1, hb1);
                if (!tag8_ok(ha2, hb2, Th)) slot_retry<true>(ph + 256,  Th, ha2, hb2);
                if (!tag8_ok(ha3, hb3, Th)) slot_retry<true>(ph + 384,  Th, ha3, hb3);
                *(u32x4*)(smem + (0 * 256 + tid) * 16)          = pack8(xa0, xb0);
                *(u32x4*)(smem + (1 * 256 + tid) * 16)          = pack8(xa1, xb1);
                *(u32x4*)(smem + (2 * 256 + tid) * 16)          = pack8(xa2, xb2);
                *(u32x4*)(smem + (3 * 256 + tid) * 16)          = pack8(xa3, xb3);
                *(u32x4*)(smem + (1024 + 0 * 256 + tid) * 16)   = pack8(ha0, hb0);
                *(u32x4*)(smem + (1024 + 1 * 256 + tid) * 16)   = pack8(ha1, hb1);
                *(u32x4*)(smem + (1024 + 2 * 256 + tid) * 16)   = pack8(ha2, hb2);
                *(u32x4*)(smem + (1024 + 3 * 256 + tid) * 16)   = pack8(ha3, hb3);
            }
            __syncthreads();

            if (tid == 0) st_flag(myflag, (unsigned int)(i + 1));  // reads done

            // ---- role0: prefetch x(i+1); latency hides under GEMM ----
            if (role == 0 && i + 1 < NS) {
                #pragma unroll
                for (int ii = 0; ii < 4; ++ii) {
                    int k0i = ii * 4 + tq;
                    const float* s = input + (long long)(m0 + (tid & 15)) * (NS * ND)
                                           + (long long)(i + 1) * ND + k0i * 32 + skoff;
                    xp[2 * ii]     = *(const float4*)s;
                    xp[2 * ii + 1] = *(const float4*)(s + 4);
                }
            }

            // ---- GEMM: 32 MFMAs, 4 acc chains; weights from warm local L2 ----
            f32x4 acc0 = {0.f,0.f,0.f,0.f}, acc1 = {0.f,0.f,0.f,0.f};
            f32x4 acc2 = {0.f,0.f,0.f,0.f}, acc3 = {0.f,0.f,0.f,0.f};
            #pragma unroll
            for (int k0i = 0; k0i < 32; k0i += 4) {
                short8 a0 = *(const short8*)(smem + (k0i + 0) * 1024 + lane * 16);
                short8 a1 = *(const short8*)(smem + (k0i + 1) * 1024 + lane * 16);
                short8 a2 = *(const short8*)(smem + (k0i + 2) * 1024 + lane * 16);
                short8 a3 = *(const short8*)(smem + (k0i + 3) * 1024 + lane * 16);
                short8 b0 = *(const short8*)(wp + (k0i + 0) * 512 + lane * 8);
                short8 b1 = *(const short8*)(wp + (k0i + 1) * 512 + lane * 8);
                short8 b2 = *(const short8*)(wp + (k0i + 2) * 512 + lane * 8);
                short8 b3 = *(const short8*)(wp + (k0i + 3) * 512 + lane * 8);
                acc0 = __builtin_amdgcn_mfma_f32_16x16x32_bf16(a0, b0, acc0, 0, 0, 0);
                acc1 = __builtin_amdgcn_mfma_f32_16x16x32_bf16(a1, b1, acc1, 0, 0, 0);
                acc2 = __builtin_amdgcn_mfma_f32_16x16x32_bf16(a2, b2, acc2, 0, 0, 0);
                acc3 = __builtin_amdgcn_mfma_f32_16x16x32_bf16(a3, b3, acc3, 0, 0, 0);
            }
            f32x4 accS = (acc0 + acc1) + (acc2 + acc3);
            __syncthreads();   // done reading A; reuse smem for gates

            float (*Gs)[16][17] = (float (*)[16][17])smem;
            {
                int u_g  = lane & 15;
                int mrow = (lane >> 4) * 4;
                #pragma unroll
                for (int r = 0; r < 4; ++r)
                    Gs[gq][mrow + r][u_g] = accS[r];
            }
            __syncthreads();

            // ---- fused LSTM cell (1 cell/thread, c in register) ----
            {
                float gi = Gs[0][m_l][u_l] + bias_i;
                float gf = Gs[1][m_l][u_l] + bias_f;
                float gg = Gs[2][m_l][u_l] + bias_g;
                float go = Gs[3][m_l][u_l] + bias_o;
                float ii = 1.f / (1.f + expf(-gi));
                float ff = 1.f / (1.f + expf(-gf));
                float gv = tanhf(gg);
                float oo = 1.f / (1.f + expf(-go));
                cReg = ff * cReg + ii * gv;
                float hn = oo * tanhf(cReg);
                unsigned short hb = bf16r(hn);

                // dual-store tagged h: plain (local L2 fast path) + sc1 (L3 truth)
                unsigned int tgE = (role == 0) ? (unsigned int)(i + 1) : (unsigned int)i;
                unsigned int tg  = (tgE << 16) | (unsigned int)hb;
                unsigned int* dst = ((role == 0)
                        ? ht0g + (i & 7) * BUF_STRIDE
                        : ht1g + ((i - 1) & 7) * BUF_STRIDE)
                    + m_l * 512 + ucell;
                *(volatile unsigned int*)dst = tg;
                __hip_atomic_store(dst, tg, __ATOMIC_RELAXED, __HIP_MEMORY_SCOPE_AGENT);

                if (role == 1) {
                    int s = i - 1;
                    __builtin_nontemporal_store(
                        hn, &out[(long long)bcell * (NS * NH) + (long long)s * NH + ucell]);
                    if (i == NS) {
                        float* dstf = out + (long long)NB * NS * NH;
                        dstf[bcell * NH + ucell] = hn;
                        dstf[NB * NH + bcell * NH + ucell] = cReg;
                    }
                }
            }
        } else {
            if (tid == 0) st_flag(myflag, (unsigned int)(i + 1));
        }

        __syncthreads();   // drain stores; separate Gs reads from next staging
    }
}

extern "C" void kernel_launch(void* const* d_in, const int* in_sizes, int n_in,
                              void* d_out, int out_size, void* d_ws, size_t ws_size,
                              hipStream_t stream) {
    const float* input = (const float*)d_in[0];
    const float* enc_h = (const float*)d_in[1];
    const float* enc_c = (const float*)d_in[2];
    const float* W_ih  = (const float*)d_in[3];
    const float* W_hh  = (const float*)d_in[4];
    const float* b_ih  = (const float*)d_in[5];
    const float* b_hh  = (const float*)d_in[6];
    float* out = (float*)d_out;
    unsigned char* ws = (unsigned char*)d_ws;

    unsigned short* wpk   = (unsigned short*)(ws + WPK_OFF);
    unsigned int*   ht0   = (unsigned int*)(ws + HT0_OFF);
    unsigned int*   ht1   = (unsigned int*)(ws + HT1_OFF);
    unsigned int*   flags = (unsigned int*)(ws + FLAGS_OFF);

    prep_weights_k<<<2048, 256, 0, stream>>>(W_ih, W_hh, (unsigned int*)wpk);
    prep_state_k<<<1024, 256, 0, stream>>>(enc_h, ht0, ht1, flags);
    lstm_persist_k<<<256, 256, 0, stream>>>(input, enc_c, b_ih, b_hh, wpk,
                                            ht0, ht1, out, flags);
}

// Round 10
// 2350.069 us; speedup vs baseline: 3.8391x; 3.8391x over previous
//
#include <hip/hip_runtime.h>

// LSTM decoder B=64,S=512,D=512,H=512,L=2 — Round 10: R7 + K-split occupancy.
// Identical to R7 (best: 2653us) EXCEPT: 512-thread blocks, 8 waves =
// (gate g, K-half kh); each wave does 16 MFMAs over its K=512 half; partial
// gates land in Gp[8][16][17] and the cell phase sums the two halves.
// Purpose: 2 waves/SIMD (was 1) to hide L2/L3 load latency. Exchange protocol,
// flags, thresholds, buffers, numerics unchanged from R7.

#define NB 64
#define NS 512
#define ND 512
#define NH 512

typedef __attribute__((ext_vector_type(8))) short short8;
typedef __attribute__((ext_vector_type(4))) float f32x4;

// ---- ws layout (bytes) ----
#define WPK_OFF   0                 // 8,388,608
#define H0_OFF    8388608           // 4 bufs * 65536
#define H1_OFF    8650752           // 2 bufs * 65536
#define FLAGS_OFF 8781824           // 256 u32
#define WPK_ELEMS_PER_ROLE (128 * 32 * 512)

__device__ __forceinline__ unsigned int pack2bf(float a, float b) {
    unsigned int ua = __builtin_bit_cast(unsigned int, a);
    unsigned int ub = __builtin_bit_cast(unsigned int, b);
    ua += 0x7fffu + ((ua >> 16) & 1u);   // RNE
    ub += 0x7fffu + ((ub >> 16) & 1u);
    return (ua >> 16) | (ub & 0xffff0000u);
}
__device__ __forceinline__ unsigned short bf16r(float a) {
    unsigned int ua = __builtin_bit_cast(unsigned int, a);
    ua += 0x7fffu + ((ua >> 16) & 1u);
    return (unsigned short)(ua >> 16);
}

// L3-coherent primitives (relaxed agent atomics -> sc1, no cache maintenance)
__device__ __forceinline__ unsigned long long ld_h64(const void* p) {
    return __hip_atomic_load((const unsigned long long*)p, __ATOMIC_RELAXED,
                             __HIP_MEMORY_SCOPE_AGENT);
}
__device__ __forceinline__ void st_h32(void* p, unsigned int v) {
    __hip_atomic_store((unsigned int*)p, v, __ATOMIC_RELAXED,
                       __HIP_MEMORY_SCOPE_AGENT);
}
__device__ __forceinline__ unsigned int ld_flag(const unsigned int* p) {
    return __hip_atomic_load(p, __ATOMIC_RELAXED, __HIP_MEMORY_SCOPE_AGENT);
}
__device__ __forceinline__ void st_flag(unsigned int* p, unsigned int v) {
    __hip_atomic_store(p, v, __ATOMIC_RELAXED, __HIP_MEMORY_SCOPE_AGENT);
}

// Repack weights into MFMA B-fragment order:
// fragment (r, nt, k0i), lane l, elem j: B[k][n], n = nt*16+(l&15), k = k0i*32+(l>>4)*8+j
__global__ void prep_weights_k(const float* __restrict__ W_ih,
                               const float* __restrict__ W_hh,
                               unsigned int* __restrict__ wpk_u32) {
    long long gid = (long long)blockIdx.x * blockDim.x + threadIdx.x; // 524288
    int l   = (int)(gid & 63);
    int k0i = (int)((gid >> 6) & 31);
    int nt  = (int)((gid >> 11) & 127);
    int r   = (int)(gid >> 18);
    int n = nt * 16 + (l & 15);
    int k = k0i * 32 + ((l >> 4) << 3);
    const float* src;
    if (k < 512) src = W_ih + ((long long)r * 2048 + n) * 512 + k;
    else         src = W_hh + ((long long)r * 2048 + n) * 512 + (k - 512);
    uint4 v;
    v.x = pack2bf(src[0], src[1]);
    v.y = pack2bf(src[2], src[3]);
    v.z = pack2bf(src[4], src[5]);
    v.w = pack2bf(src[6], src[7]);
    ((uint4*)wpk_u32)[gid] = v;
}

__global__ void prep_state_k(const float* __restrict__ eh,
                             unsigned short* __restrict__ h0base,
                             unsigned short* __restrict__ h1base,
                             unsigned int* __restrict__ flags) {
    int i = blockIdx.x * blockDim.x + threadIdx.x;  // 32768
    if (i < NB * NH) {
        unsigned short hb = bf16r(eh[i]);
        (h0base + 3 * 32768)[i] = hb;   // h0_{-1} -> buf (-1)&3 = 3
        (h1base + 1 * 32768)[i] = hb;   // h1_{-1} -> buf (-1)&1 = 1
    }
    if (i < 256) flags[i] = 0;
}

__global__ __launch_bounds__(512, 2)
void lstm_persist_k(const float* __restrict__ input,
                    const float* __restrict__ enc_c,
                    const float* __restrict__ b_ih,
                    const float* __restrict__ b_hh,
                    const unsigned short* __restrict__ wpk,
                    unsigned short* __restrict__ h0base,
                    unsigned short* __restrict__ h1base,
                    float* __restrict__ out,
                    unsigned int* __restrict__ flags) {
    __shared__ alignas(16) unsigned char smem[32768];   // A tile (fragment-packed)
    __shared__ float Gp[8][16][17];                     // partial gates per wave
    const int bid  = blockIdx.x;
    const int role = bid >> 7;             // 0: layer0(i), 1: layer1(i-1)
    const int lb   = bid & 127;
    const int ms   = lb >> 5;              // batch block 0..3 (sync group)
    const int us   = lb & 31;              // unit block 0..31
    const int m0   = ms << 4;
    const int tid  = threadIdx.x;
    const int lane = tid & 63;
    const int w    = tid >> 6;             // wave 0..7
    const int g    = __builtin_amdgcn_readfirstlane(w & 3);   // gate
    const int kh   = __builtin_amdgcn_readfirstlane(w >> 2);  // K-half

    // wave's B base: tile (g,us), K-half kh (16 chunks of 512 bf16 each)
    const unsigned short* wp = wpk + (long long)role * WPK_ELEMS_PER_ROLE
                             + (long long)(g * 32 + us) * (32 * 512)
                             + (long long)kh * 16 * 512;
    const unsigned char* aBase = smem + kh * 16384;

    unsigned int* myflag   = flags + (ms << 6) + (role << 5) + us;
    const unsigned int* gf = flags + (ms << 6) + lane;

    // ---- cell state + biases (threads 0..255 own the 256 cells) ----
    const int m_l = (tid >> 4) & 15, u_l = tid & 15;
    const int bcell = m0 + m_l;
    const int ucell = us * 16 + u_l;
    float cReg = 0.f, bias_i = 0.f, bias_f = 0.f, bias_g = 0.f, bias_o = 0.f;
    if (tid < 256) {
        cReg = enc_c[bcell * NH + ucell];
        const long long br = (long long)role * 2048;
        bias_i = b_ih[br + 0 * 512 + ucell] + b_hh[br + 0 * 512 + ucell];
        bias_f = b_ih[br + 1 * 512 + ucell] + b_hh[br + 1 * 512 + ucell];
        bias_g = b_ih[br + 2 * 512 + ucell] + b_hh[br + 2 * 512 + ucell];
        bias_o = b_ih[br + 3 * 512 + ucell] + b_hh[br + 3 * 512 + ucell];
    }

    // staging: thread handles 4 slots: {tid, 512+tid} = x-part, {1024+tid, 1536+tid} = h-part
    // slot sid: chunk = sid>>6, row = sid&15, koff = ((sid>>4)&3)*8
    const int srow  = tid & 15;
    const int skoff = ((tid >> 4) & 3) << 3;

    // ---- role0: prefetch x(0) into registers (2 slots = 4 float4) ----
    float4 xp[4];
    if (role == 0) {
        #pragma unroll
        for (int j2 = 0; j2 < 2; ++j2) {
            int sid = j2 * 512 + tid;
            int k = (sid >> 6) * 32 + skoff;
            const float* s = input + (long long)(m0 + srow) * (NS * ND) + k;
            xp[2 * j2]     = *(const float4*)s;
            xp[2 * j2 + 1] = *(const float4*)(s + 4);
        }
    }

    for (int i = 0; i <= NS; ++i) {
        const bool active = (role == 0) ? (i < NS) : (i >= 1);

        // ---- A: role0 pre-poll x staging (regs -> LDS x-region) ----
        if (role == 0 && i < NS) {
            #pragma unroll
            for (int j2 = 0; j2 < 2; ++j2) {
                int sid = j2 * 512 + tid;
                float4 lo = xp[2 * j2], hi = xp[2 * j2 + 1];
                uint4 val;
                val.x = pack2bf(lo.x, lo.y);
                val.y = pack2bf(lo.z, lo.w);
                val.z = pack2bf(hi.x, hi.y);
                val.w = pack2bf(hi.z, hi.w);
                *(uint4*)(smem + sid * 16) = val;
            }
        }

        // ---- B: poll (role-asymmetric epochs, identical to R7) ----
        if (i > 0) {
            if (tid < 64) {
                unsigned int thr;
                if (role == 0)
                    thr = (lane < 32) ? (unsigned int)i
                                      : (unsigned int)(i >= 2 ? i - 2 : 0);
                else
                    thr = (unsigned int)i;
                for (;;) {
                    unsigned int v = ld_flag(gf);
                    if (__ballot(v >= thr) == 0xFFFFFFFFFFFFFFFFULL) break;
                    __builtin_amdgcn_s_sleep(1);
                }
            }
            __syncthreads();   // flag observed -> safe to read h data
        }

        if (active) {
            const unsigned short* h0prev = h0base + (((i - 1) & 3) << 15); // h0_{i-1}
            const unsigned short* hp = (role == 0) ? h0prev
                                     : h1base + ((i & 1) << 15);          // h1_{i-2}

            // ---- C: stage remaining A-parts ----
            if (role == 1) {
                // x-part = h0_{i-1} (slots tid, 512+tid)
                #pragma unroll
                for (int j2 = 0; j2 < 2; ++j2) {
                    int sid = j2 * 512 + tid;
                    int k = (sid >> 6) * 32 + skoff;
                    const unsigned long long* p =
                        (const unsigned long long*)(h0prev + (long long)(m0 + srow) * 512 + k);
                    unsigned long long lo = ld_h64(p);
                    unsigned long long hi = ld_h64(p + 1);
                    uint4 val;
                    val.x = (unsigned int)lo; val.y = (unsigned int)(lo >> 32);
                    val.z = (unsigned int)hi; val.w = (unsigned int)(hi >> 32);
                    *(uint4*)(smem + sid * 16) = val;
                }
            }
            // h-part (both roles; slots 1024+tid, 1536+tid)
            #pragma unroll
            for (int j2 = 2; j2 < 4; ++j2) {
                int sid = j2 * 512 + tid;
                int k = ((sid >> 6) - 16) * 32 + skoff;
                const unsigned long long* p =
                    (const unsigned long long*)(hp + (long long)(m0 + srow) * 512 + k);
                unsigned long long lo = ld_h64(p);
                unsigned long long hi = ld_h64(p + 1);
                uint4 val;
                val.x = (unsigned int)lo; val.y = (unsigned int)(lo >> 32);
                val.z = (unsigned int)hi; val.w = (unsigned int)(hi >> 32);
                *(uint4*)(smem + sid * 16) = val;
            }
            __syncthreads();

            // ---- GEMM: wave (g,kh) -> 16 MFMAs over its K-half, 2 acc chains ----
            f32x4 acc0 = {0.f,0.f,0.f,0.f}, acc1 = {0.f,0.f,0.f,0.f};
            #pragma unroll
            for (int j = 0; j < 16; j += 2) {
                short8 a0 = *(const short8*)(aBase + (j + 0) * 1024 + lane * 16);
                short8 a1 = *(const short8*)(aBase + (j + 1) * 1024 + lane * 16);
                short8 b0 = *(const short8*)(wp + (j + 0) * 512 + lane * 8);
                short8 b1 = *(const short8*)(wp + (j + 1) * 512 + lane * 8);
                acc0 = __builtin_amdgcn_mfma_f32_16x16x32_bf16(a0, b0, acc0, 0, 0, 0);
                acc1 = __builtin_amdgcn_mfma_f32_16x16x32_bf16(a1, b1, acc1, 0, 0, 0);
            }
            f32x4 accS = acc0 + acc1;

            // partial gates to LDS (separate region, no A overlap)
            {
                int u_g  = lane & 15;
                int mrow = (lane >> 4) * 4;
                #pragma unroll
                for (int r = 0; r < 4; ++r)
                    Gp[w][mrow + r][u_g] = accS[r];
            }
            __syncthreads();

            // ---- fused LSTM cell: threads 0..255, sum the two K-half partials ----
            if (tid < 256) {
                float gi = Gp[0][m_l][u_l] + Gp[4][m_l][u_l] + bias_i;
                float gf = Gp[1][m_l][u_l] + Gp[5][m_l][u_l] + bias_f;
                float gg = Gp[2][m_l][u_l] + Gp[6][m_l][u_l] + bias_g;
                float go = Gp[3][m_l][u_l] + Gp[7][m_l][u_l] + bias_o;
                float ii = 1.f / (1.f + expf(-gi));
                float ff = 1.f / (1.f + expf(-gf));
                float gv = tanhf(gg);
                float oo = 1.f / (1.f + expf(-go));
                cReg = ff * cReg + ii * gv;
                float hn = oo * tanhf(cReg);

                // publish h (packed bf16 pair) via sc1 store
                float hn_p = __shfl_xor(hn, 1);
                if ((u_l & 1) == 0) {
                    unsigned int pk = pack2bf(hn, hn_p);
                    unsigned short* hbuf = (role == 0)
                        ? h0base + ((i & 3) << 15)             // h0_i
                        : h1base + (((i - 1) & 1) << 15);      // h1_{i-1}
                    st_h32((unsigned int*)hbuf + ((bcell * NH + ucell) >> 1), pk);
                }
                if (role == 1) {
                    int s = i - 1;
                    out[(long long)bcell * (NS * NH) + (long long)s * NH + ucell] = hn;
                    if (i == NS) {
                        float* dst = out + (long long)NB * NS * NH;
                        dst[bcell * NH + ucell] = hn;
                        dst[NB * NH + bcell * NH + ucell] = cReg;
                    }
                }
            }
        }

        // ---- D: drain, publish flag, then prefetch next x ----
        if (i < NS) {
            __syncthreads();   // drains vmcnt per wave -> h stores acked at L3
            if (tid == 0) st_flag(myflag, (unsigned int)(i + 1));
            if (role == 0 && i + 1 < NS) {
                #pragma unroll
                for (int j2 = 0; j2 < 2; ++j2) {
                    int sid = j2 * 512 + tid;
                    int k = (sid >> 6) * 32 + skoff;
                    const float* s = input + (long long)(m0 + srow) * (NS * ND)
                                           + (long long)(i + 1) * ND + k;
                    xp[2 * j2]     = *(const float4*)s;
                    xp[2 * j2 + 1] = *(const float4*)(s + 4);
                }
            }
        }
    }
}

extern "C" void kernel_launch(void* const* d_in, const int* in_sizes, int n_in,
                              void* d_out, int out_size, void* d_ws, size_t ws_size,
                              hipStream_t stream) {
    const float* input = (const float*)d_in[0];
    const float* enc_h = (const float*)d_in[1];
    const float* enc_c = (const float*)d_in[2];
    const float* W_ih  = (const float*)d_in[3];
    const float* W_hh  = (const float*)d_in[4];
    const float* b_ih  = (const float*)d_in[5];
    const float* b_hh  = (const float*)d_in[6];
    float* out = (float*)d_out;
    unsigned char* ws = (unsigned char*)d_ws;

    unsigned short* wpk    = (unsigned short*)(ws + WPK_OFF);
    unsigned short* h0base = (unsigned short*)(ws + H0_OFF);
    unsigned short* h1base = (unsigned short*)(ws + H1_OFF);
    unsigned int*   flags  = (unsigned int*)(ws + FLAGS_OFF);

    prep_weights_k<<<2048, 256, 0, stream>>>(W_ih, W_hh, (unsigned int*)wpk);
    prep_state_k<<<128, 256, 0, stream>>>(enc_h, h0base, h1base, flags);
    lstm_persist_k<<<256, 512, 0, stream>>>(input, enc_c, b_ih, b_hh, wpk,
                                            h0base, h1base, out, flags);
}

// Round 11
// 2019.580 us; speedup vs baseline: 4.4673x; 1.1636x over previous
//
#include <hip/hip_runtime.h>

// LSTM decoder B=64,S=512,D=512,H=512,L=2 — Round 11: R10 + weights in regs.
// Identical to R10 (best: 2350us) EXCEPT: each wave's 16 B-fragments (K-half)
// are loaded ONCE before the t-loop into 64 VGPRs (short8 x16) and held live
// with asm keep-alives. GEMM inner loop = ds_read_b128 + MFMA only (no VMEM).
// Exchange protocol, flags, buffers, staging, numerics unchanged from R10.

#define NB 64
#define NS 512
#define ND 512
#define NH 512

typedef __attribute__((ext_vector_type(8))) short short8;
typedef __attribute__((ext_vector_type(4))) float f32x4;

// ---- ws layout (bytes) ----
#define WPK_OFF   0                 // 8,388,608
#define H0_OFF    8388608           // 4 bufs * 65536
#define H1_OFF    8650752           // 2 bufs * 65536
#define FLAGS_OFF 8781824           // 256 u32
#define WPK_ELEMS_PER_ROLE (128 * 32 * 512)

__device__ __forceinline__ unsigned int pack2bf(float a, float b) {
    unsigned int ua = __builtin_bit_cast(unsigned int, a);
    unsigned int ub = __builtin_bit_cast(unsigned int, b);
    ua += 0x7fffu + ((ua >> 16) & 1u);   // RNE
    ub += 0x7fffu + ((ub >> 16) & 1u);
    return (ua >> 16) | (ub & 0xffff0000u);
}
__device__ __forceinline__ unsigned short bf16r(float a) {
    unsigned int ua = __builtin_bit_cast(unsigned int, a);
    ua += 0x7fffu + ((ua >> 16) & 1u);
    return (unsigned short)(ua >> 16);
}

// L3-coherent primitives (relaxed agent atomics -> sc1, no cache maintenance)
__device__ __forceinline__ unsigned long long ld_h64(const void* p) {
    return __hip_atomic_load((const unsigned long long*)p, __ATOMIC_RELAXED,
                             __HIP_MEMORY_SCOPE_AGENT);
}
__device__ __forceinline__ void st_h32(void* p, unsigned int v) {
    __hip_atomic_store((unsigned int*)p, v, __ATOMIC_RELAXED,
                       __HIP_MEMORY_SCOPE_AGENT);
}
__device__ __forceinline__ unsigned int ld_flag(const unsigned int* p) {
    return __hip_atomic_load(p, __ATOMIC_RELAXED, __HIP_MEMORY_SCOPE_AGENT);
}
__device__ __forceinline__ void st_flag(unsigned int* p, unsigned int v) {
    __hip_atomic_store(p, v, __ATOMIC_RELAXED, __HIP_MEMORY_SCOPE_AGENT);
}

// Repack weights into MFMA B-fragment order:
// fragment (r, nt, k0i), lane l, elem j: B[k][n], n = nt*16+(l&15), k = k0i*32+(l>>4)*8+j
__global__ void prep_weights_k(const float* __restrict__ W_ih,
                               const float* __restrict__ W_hh,
                               unsigned int* __restrict__ wpk_u32) {
    long long gid = (long long)blockIdx.x * blockDim.x + threadIdx.x; // 524288
    int l   = (int)(gid & 63);
    int k0i = (int)((gid >> 6) & 31);
    int nt  = (int)((gid >> 11) & 127);
    int r   = (int)(gid >> 18);
    int n = nt * 16 + (l & 15);
    int k = k0i * 32 + ((l >> 4) << 3);
    const float* src;
    if (k < 512) src = W_ih + ((long long)r * 2048 + n) * 512 + k;
    else         src = W_hh + ((long long)r * 2048 + n) * 512 + (k - 512);
    uint4 v;
    v.x = pack2bf(src[0], src[1]);
    v.y = pack2bf(src[2], src[3]);
    v.z = pack2bf(src[4], src[5]);
    v.w = pack2bf(src[6], src[7]);
    ((uint4*)wpk_u32)[gid] = v;
}

__global__ void prep_state_k(const float* __restrict__ eh,
                             unsigned short* __restrict__ h0base,
                             unsigned short* __restrict__ h1base,
                             unsigned int* __restrict__ flags) {
    int i = blockIdx.x * blockDim.x + threadIdx.x;  // 32768
    if (i < NB * NH) {
        unsigned short hb = bf16r(eh[i]);
        (h0base + 3 * 32768)[i] = hb;   // h0_{-1} -> buf (-1)&3 = 3
        (h1base + 1 * 32768)[i] = hb;   // h1_{-1} -> buf (-1)&1 = 1
    }
    if (i < 256) flags[i] = 0;
}

__global__ __launch_bounds__(512, 1)
void lstm_persist_k(const float* __restrict__ input,
                    const float* __restrict__ enc_c,
                    const float* __restrict__ b_ih,
                    const float* __restrict__ b_hh,
                    const unsigned short* __restrict__ wpk,
                    unsigned short* __restrict__ h0base,
                    unsigned short* __restrict__ h1base,
                    float* __restrict__ out,
                    unsigned int* __restrict__ flags) {
    __shared__ alignas(16) unsigned char smem[32768];   // A tile (fragment-packed)
    __shared__ float Gp[8][16][17];                     // partial gates per wave
    const int bid  = blockIdx.x;
    const int role = bid >> 7;             // 0: layer0(i), 1: layer1(i-1)
    const int lb   = bid & 127;
    const int ms   = lb >> 5;              // batch block 0..3 (sync group)
    const int us   = lb & 31;              // unit block 0..31
    const int m0   = ms << 4;
    const int tid  = threadIdx.x;
    const int lane = tid & 63;
    const int w    = tid >> 6;             // wave 0..7
    const int g    = __builtin_amdgcn_readfirstlane(w & 3);   // gate
    const int kh   = __builtin_amdgcn_readfirstlane(w >> 2);  // K-half

    // wave's B base: tile (g,us), K-half kh (16 chunks of 512 bf16 each)
    const unsigned short* wp = wpk + (long long)role * WPK_ELEMS_PER_ROLE
                             + (long long)(g * 32 + us) * (32 * 512)
                             + (long long)kh * 16 * 512;
    const unsigned char* aBase = smem + kh * 16384;

    // ---- pin this wave's 16 B-fragments in registers (once) ----
    short8 wreg[16];
    #pragma unroll
    for (int j = 0; j < 16; ++j)
        wreg[j] = *(const short8*)(wp + j * 512 + lane * 8);
    #pragma unroll
    for (int j = 0; j < 16; ++j)
        asm volatile("" : "+v"(wreg[j]));   // opaque -> stays live, no remat

    unsigned int* myflag   = flags + (ms << 6) + (role << 5) + us;
    const unsigned int* gf = flags + (ms << 6) + lane;

    // ---- cell state + biases (threads 0..255 own the 256 cells) ----
    const int m_l = (tid >> 4) & 15, u_l = tid & 15;
    const int bcell = m0 + m_l;
    const int ucell = us * 16 + u_l;
    float cReg = 0.f, bias_i = 0.f, bias_f = 0.f, bias_g = 0.f, bias_o = 0.f;
    if (tid < 256) {
        cReg = enc_c[bcell * NH + ucell];
        const long long br = (long long)role * 2048;
        bias_i = b_ih[br + 0 * 512 + ucell] + b_hh[br + 0 * 512 + ucell];
        bias_f = b_ih[br + 1 * 512 + ucell] + b_hh[br + 1 * 512 + ucell];
        bias_g = b_ih[br + 2 * 512 + ucell] + b_hh[br + 2 * 512 + ucell];
        bias_o = b_ih[br + 3 * 512 + ucell] + b_hh[br + 3 * 512 + ucell];
    }

    // staging: thread handles 4 slots: {tid, 512+tid} = x-part, {1024+tid, 1536+tid} = h-part
    const int srow  = tid & 15;
    const int skoff = ((tid >> 4) & 3) << 3;

    // ---- role0: prefetch x(0) into registers ----
    float4 xp[4];
    if (role == 0) {
        #pragma unroll
        for (int j2 = 0; j2 < 2; ++j2) {
            int sid = j2 * 512 + tid;
            int k = (sid >> 6) * 32 + skoff;
            const float* s = input + (long long)(m0 + srow) * (NS * ND) + k;
            xp[2 * j2]     = *(const float4*)s;
            xp[2 * j2 + 1] = *(const float4*)(s + 4);
        }
    }

    for (int i = 0; i <= NS; ++i) {
        const bool active = (role == 0) ? (i < NS) : (i >= 1);

        // ---- A: role0 pre-poll x staging (regs -> LDS x-region) ----
        if (role == 0 && i < NS) {
            #pragma unroll
            for (int j2 = 0; j2 < 2; ++j2) {
                int sid = j2 * 512 + tid;
                float4 lo = xp[2 * j2], hi = xp[2 * j2 + 1];
                uint4 val;
                val.x = pack2bf(lo.x, lo.y);
                val.y = pack2bf(lo.z, lo.w);
                val.z = pack2bf(hi.x, hi.y);
                val.w = pack2bf(hi.z, hi.w);
                *(uint4*)(smem + sid * 16) = val;
            }
        }

        // ---- B: poll (role-asymmetric epochs) ----
        if (i > 0) {
            if (tid < 64) {
                unsigned int thr;
                if (role == 0)
                    thr = (lane < 32) ? (unsigned int)i
                                      : (unsigned int)(i >= 2 ? i - 2 : 0);
                else
                    thr = (unsigned int)i;
                for (;;) {
                    unsigned int v = ld_flag(gf);
                    if (__ballot(v >= thr) == 0xFFFFFFFFFFFFFFFFULL) break;
                    __builtin_amdgcn_s_sleep(1);
                }
            }
            __syncthreads();   // flag observed -> safe to read h data
        }

        if (active) {
            const unsigned short* h0prev = h0base + (((i - 1) & 3) << 15); // h0_{i-1}
            const unsigned short* hp = (role == 0) ? h0prev
                                     : h1base + ((i & 1) << 15);          // h1_{i-2}

            // ---- C: stage remaining A-parts ----
            if (role == 1) {
                // x-part = h0_{i-1} (slots tid, 512+tid)
                #pragma unroll
                for (int j2 = 0; j2 < 2; ++j2) {
                    int sid = j2 * 512 + tid;
                    int k = (sid >> 6) * 32 + skoff;
                    const unsigned long long* p =
                        (const unsigned long long*)(h0prev + (long long)(m0 + srow) * 512 + k);
                    unsigned long long lo = ld_h64(p);
                    unsigned long long hi = ld_h64(p + 1);
                    uint4 val;
                    val.x = (unsigned int)lo; val.y = (unsigned int)(lo >> 32);
                    val.z = (unsigned int)hi; val.w = (unsigned int)(hi >> 32);
                    *(uint4*)(smem + sid * 16) = val;
                }
            }
            // h-part (both roles; slots 1024+tid, 1536+tid)
            #pragma unroll
            for (int j2 = 2; j2 < 4; ++j2) {
                int sid = j2 * 512 + tid;
                int k = ((sid >> 6) - 16) * 32 + skoff;
                const unsigned long long* p =
                    (const unsigned long long*)(hp + (long long)(m0 + srow) * 512 + k);
                unsigned long long lo = ld_h64(p);
                unsigned long long hi = ld_h64(p + 1);
                uint4 val;
                val.x = (unsigned int)lo; val.y = (unsigned int)(lo >> 32);
                val.z = (unsigned int)hi; val.w = (unsigned int)(hi >> 32);
                *(uint4*)(smem + sid * 16) = val;
            }
            __syncthreads();

            // ---- GEMM: wave (g,kh) -> 16 MFMAs, B from registers ----
            f32x4 acc0 = {0.f,0.f,0.f,0.f}, acc1 = {0.f,0.f,0.f,0.f};
            #pragma unroll
            for (int j = 0; j < 16; j += 2) {
                short8 a0 = *(const short8*)(aBase + (j + 0) * 1024 + lane * 16);
                short8 a1 = *(const short8*)(aBase + (j + 1) * 1024 + lane * 16);
                acc0 = __builtin_amdgcn_mfma_f32_16x16x32_bf16(a0, wreg[j + 0], acc0, 0, 0, 0);
                acc1 = __builtin_amdgcn_mfma_f32_16x16x32_bf16(a1, wreg[j + 1], acc1, 0, 0, 0);
            }
            f32x4 accS = acc0 + acc1;

            // partial gates to LDS (separate region, no A overlap)
            {
                int u_g  = lane & 15;
                int mrow = (lane >> 4) * 4;
                #pragma unroll
                for (int r = 0; r < 4; ++r)
                    Gp[w][mrow + r][u_g] = accS[r];
            }
            __syncthreads();

            // ---- fused LSTM cell: threads 0..255, sum the two K-half partials ----
            if (tid < 256) {
                float gi = Gp[0][m_l][u_l] + Gp[4][m_l][u_l] + bias_i;
                float gf = Gp[1][m_l][u_l] + Gp[5][m_l][u_l] + bias_f;
                float gg = Gp[2][m_l][u_l] + Gp[6][m_l][u_l] + bias_g;
                float go = Gp[3][m_l][u_l] + Gp[7][m_l][u_l] + bias_o;
                float ii = 1.f / (1.f + expf(-gi));
                float ff = 1.f / (1.f + expf(-gf));
                float gv = tanhf(gg);
                float oo = 1.f / (1.f + expf(-go));
                cReg = ff * cReg + ii * gv;
                float hn = oo * tanhf(cReg);

                // publish h (packed bf16 pair) via sc1 store
                float hn_p = __shfl_xor(hn, 1);
                if ((u_l & 1) == 0) {
                    unsigned int pk = pack2bf(hn, hn_p);
                    unsigned short* hbuf = (role == 0)
                        ? h0base + ((i & 3) << 15)             // h0_i
                        : h1base + (((i - 1) & 1) << 15);      // h1_{i-1}
                    st_h32((unsigned int*)hbuf + ((bcell * NH + ucell) >> 1), pk);
                }
                if (role == 1) {
                    int s = i - 1;
                    out[(long long)bcell * (NS * NH) + (long long)s * NH + ucell] = hn;
                    if (i == NS) {
                        float* dst = out + (long long)NB * NS * NH;
                        dst[bcell * NH + ucell] = hn;
                        dst[NB * NH + bcell * NH + ucell] = cReg;
                    }
                }
            }
        }

        // ---- D: drain, publish flag, then prefetch next x ----
        if (i < NS) {
            __syncthreads();   // drains vmcnt per wave -> h stores acked at L3
            if (tid == 0) st_flag(myflag, (unsigned int)(i + 1));
            if (role == 0 && i + 1 < NS) {
                #pragma unroll
                for (int j2 = 0; j2 < 2; ++j2) {
                    int sid = j2 * 512 + tid;
                    int k = (sid >> 6) * 32 + skoff;
                    const float* s = input + (long long)(m0 + srow) * (NS * ND)
                                           + (long long)(i + 1) * ND + k;
                    xp[2 * j2]     = *(const float4*)s;
                    xp[2 * j2 + 1] = *(const float4*)(s + 4);
                }
            }
        }
    }
}

extern "C" void kernel_launch(void* const* d_in, const int* in_sizes, int n_in,
                              void* d_out, int out_size, void* d_ws, size_t ws_size,
                              hipStream_t stream) {
    const float* input = (const float*)d_in[0];
    const float* enc_h = (const float*)d_in[1];
    const float* enc_c = (const float*)d_in[2];
    const float* W_ih  = (const float*)d_in[3];
    const float* W_hh  = (const float*)d_in[4];
    const float* b_ih  = (const float*)d_in[5];
    const float* b_hh  = (const float*)d_in[6];
    float* out = (float*)d_out;
    unsigned char* ws = (unsigned char*)d_ws;

    unsigned short* wpk    = (unsigned short*)(ws + WPK_OFF);
    unsigned short* h0base = (unsigned short*)(ws + H0_OFF);
    unsigned short* h1base = (unsigned short*)(ws + H1_OFF);
    unsigned int*   flags  = (unsigned int*)(ws + FLAGS_OFF);

    prep_weights_k<<<2048, 256, 0, stream>>>(W_ih, W_hh, (unsigned int*)wpk);
    prep_state_k<<<128, 256, 0, stream>>>(enc_h, h0base, h1base, flags);
    lstm_persist_k<<<256, 512, 0, stream>>>(input, enc_c, b_ih, b_hh, wpk,
                                            h0base, h1base, out, flags);
}